// Round 10
// baseline (172.055 us; speedup 1.0000x reference)
//
#include <hip/hip_runtime.h>

typedef __attribute__((ext_vector_type(8))) short short8;
typedef __attribute__((ext_vector_type(4))) short short4v;
typedef __attribute__((ext_vector_type(4))) float floatx4;
typedef __attribute__((ext_vector_type(16))) float floatx16;

#define HIDDEN 768
#define NH 12
#define HD 64
#define SEQ 2048
#define BATCH 2
#define BHN (BATCH*NH)      // 24
#define MTOT (BATCH*SEQ)    // 4096
#define NQKV (3*HIDDEN)     // 2304
#define QSCALE 0.1803368801111204f   // 0.125 * log2(e): scores in log2 domain

__device__ __forceinline__ short f2bf(float f) {
  union { float f; unsigned u; } v; v.f = f;
  unsigned r = v.u + 0x7FFFu + ((v.u >> 16) & 1u);   // RNE
  return (short)(r >> 16);
}
__device__ __forceinline__ unsigned bfrne(float f) {
  unsigned u = __float_as_uint(f);
  return u + 0x7FFFu + ((u >> 16) & 1u);
}
__device__ __forceinline__ unsigned pk2(float a, float b) {
  return __builtin_amdgcn_perm(bfrne(b), bfrne(a), 0x07060302u);
}
__device__ __forceinline__ float bf2f(short s) {
  return __uint_as_float(((unsigned)(unsigned short)s) << 16);
}
__device__ __forceinline__ floatx4 mfma_bf16(short8 a, short8 b, floatx4 c) {
  return __builtin_amdgcn_mfma_f32_16x16x32_bf16(a, b, c, 0, 0, 0);
}
__device__ __forceinline__ floatx16 mfma32(short8 a, short8 b, floatx16 c) {
  return __builtin_amdgcn_mfma_f32_32x32x16_bf16(a, b, c, 0, 0, 0);
}
__device__ __forceinline__ short8 ld8(const short* p) {
  return *reinterpret_cast<const short8*>(p);
}
// async global->LDS DMA, 16B per lane. LDS dst = wave-uniform base + lane*16.
__device__ __forceinline__ void glds16(const short* g, short* l) {
  __builtin_amdgcn_global_load_lds(
      (const __attribute__((address_space(1))) void*)g,
      (__attribute__((address_space(3))) void*)l, 16, 0, 0);
}

// ---------------- fused prep: X cvt + both weight transposes, one launch ----------------
__global__ __launch_bounds__(256) void prep(const float* __restrict__ X,
                                            const float* __restrict__ Wqkv,
                                            const float* __restrict__ Wout,
                                            short* __restrict__ Xb,
                                            short* __restrict__ WqkvT,
                                            short* __restrict__ WoutT) {
  __shared__ short t[64][72];
  int bx = blockIdx.x;
  if (bx < 1536) {
    int i = (bx * 256 + threadIdx.x) * 8;
    const float4* s = reinterpret_cast<const float4*>(X + i);
    float4 v0 = s[0], v1 = s[1];
    short8 o;
    o[0] = f2bf(v0.x); o[1] = f2bf(v0.y); o[2] = f2bf(v0.z); o[3] = f2bf(v0.w);
    o[4] = f2bf(v1.x); o[5] = f2bf(v1.y); o[6] = f2bf(v1.z); o[7] = f2bf(v1.w);
    *reinterpret_cast<short8*>(Xb + i) = o;
    return;
  }
  int tt = bx - 1536;            // 0..575
  int bxx = tt % 48, by = tt / 48;
  const float* W; short* WT; int N; int nb;
  if (bxx < 36) { W = Wqkv; WT = WqkvT; N = NQKV;   nb = bxx * 64; }
  else          { W = Wout; WT = WoutT; N = HIDDEN; nb = (bxx - 36) * 64; }
  int kb = by * 64;
  int tid = threadIdx.x;
  {
    int k  = tid >> 2;
    int n0 = (tid & 3) << 4;
    const float4* src = reinterpret_cast<const float4*>(W + (size_t)(kb + k) * N + nb + n0);
    #pragma unroll
    for (int c = 0; c < 4; ++c) {
      float4 v = src[c];
      t[n0 + c*4 + 0][k] = f2bf(v.x);
      t[n0 + c*4 + 1][k] = f2bf(v.y);
      t[n0 + c*4 + 2][k] = f2bf(v.z);
      t[n0 + c*4 + 3][k] = f2bf(v.w);
    }
  }
  __syncthreads();
  {
    int n  = tid >> 2;
    int k0 = (tid & 3) << 4;
    const short8* row = reinterpret_cast<const short8*>(&t[n][k0]);
    short8* dst = reinterpret_cast<short8*>(WT + (size_t)(nb + n) * HIDDEN + kb + k0);
    dst[0] = row[0];
    dst[1] = row[1];
  }
}

// ---------------- GEMM1: 128x128 tile, BK=32, glds16 staging (R8 known-good) ----------------
__global__ __launch_bounds__(256) void gemm_qkv(const short* __restrict__ Xb,
                                                const short* __restrict__ WT,
                                                const float* __restrict__ bias,
                                                short* __restrict__ Qb,
                                                short* __restrict__ Kb,
                                                short* __restrict__ VTb) {
  __shared__ short As[128 * 32];
  __shared__ short Bs[128 * 32];
  int m0 = blockIdx.x * 128, n0 = blockIdx.y * 128;
  int tid = threadIdx.x;
  int lane = tid & 63, wv = tid >> 6;
  int wm = (wv >> 1) << 6, wn = (wv & 1) << 6;
  int quad = lane >> 4, l16 = lane & 15;

  int srow = lane >> 2;
  int schunk = (lane & 3) ^ ((lane >> 3) & 3);
  const short* ag0 = Xb + (size_t)(m0 + wv * 32 + srow) * HIDDEN + schunk * 8;
  const short* ag1 = ag0 + 16 * HIDDEN;
  const short* bg0 = WT + (size_t)(n0 + wv * 32 + srow) * HIDDEN + schunk * 8;
  const short* bg1 = bg0 + 16 * HIDDEN;
  short* lA0 = As + wv * 1024;
  short* lB0 = Bs + wv * 1024;

  int sw = ((l16 >> 1) & 3);
  int aoff = (wm + l16) * 32 + ((quad ^ sw) << 3);
  int boff = (wn + l16) * 32 + ((quad ^ sw) << 3);

  floatx4 acc[4][4] = {};
  for (int kk = 0; kk < HIDDEN; kk += 32) {
    __syncthreads();
    glds16(ag0, lA0);
    glds16(ag1, lA0 + 512);
    glds16(bg0, lB0);
    glds16(bg1, lB0 + 512);
    ag0 += 32; ag1 += 32; bg0 += 32; bg1 += 32;
    __syncthreads();
    short8 af[4], bfr[4];
    #pragma unroll
    for (int i = 0; i < 4; ++i)
      af[i] = *reinterpret_cast<const short8*>(&As[aoff + i * 512]);
    #pragma unroll
    for (int j = 0; j < 4; ++j)
      bfr[j] = *reinterpret_cast<const short8*>(&Bs[boff + j * 512]);
    #pragma unroll
    for (int i = 0; i < 4; ++i)
      #pragma unroll
      for (int j = 0; j < 4; ++j)
        acc[i][j] = mfma_bf16(af[i], bfr[j], acc[i][j]);
  }
  int colbase = n0 + wn;
  int part = colbase / HIDDEN;
  #pragma unroll
  for (int j = 0; j < 4; ++j) {
    int col = colbase + j * 16 + l16;
    float bs = bias[col];
    int rem = col - part * HIDDEN;
    int h = rem >> 6, d = rem & 63;
    #pragma unroll
    for (int i = 0; i < 4; ++i) {
      #pragma unroll
      for (int r = 0; r < 4; ++r) {
        int row = m0 + wm + i * 16 + quad * 4 + r;
        float v = acc[i][j][r] + bs;
        int bb = row >> 11, s = row & 2047;
        int bh = bb * NH + h;
        if (part == 0) {
          Qb[((size_t)bh * SEQ + s) * HD + d] = f2bf(v * QSCALE);
        } else if (part == 1) {
          Kb[((size_t)bh * SEQ + s) * HD + d] = f2bf(v);
        } else {
          VTb[((size_t)bh * HD + d) * SEQ + s] = f2bf(v);
        }
      }
    }
  }
}

// ---------------- flash attention partials: uniform 512-kv chunks ----------------
__global__ __launch_bounds__(256, 4) void attn_partial(const short* __restrict__ Qb,
                                                       const short* __restrict__ Kb,
                                                       const short* __restrict__ VTb,
                                                       short* __restrict__ PO,
                                                       float* __restrict__ PM,
                                                       float* __restrict__ PL) {
  __shared__ __align__(16) char lds[32768];   // K: buf*8192 ; V: 16384 + buf*8192
  int blk = blockIdx.x;
  int cls = blk & 7;
  int j   = blk >> 3;            // 0..119
  int headsel = j / 40;
  int bh  = cls + 8 * headsel;
  int cidx = 39 - (j - headsel * 40);   // heavy first
  int qt, c;
  if (cidx < 4)       { qt = cidx;                  c = 0; }
  else if (cidx < 12) { qt = 4 + ((cidx - 4) >> 1); c = (cidx - 4) & 1; }
  else if (cidx < 24) { int t = cidx - 12; int q3 = t / 3; qt = 8 + q3; c = t - 3 * q3; }
  else                { int t = cidx - 24; qt = 12 + (t >> 2); c = t & 3; }
  int g = qt >> 2, p = qt & 3;
  int idx = bh * 40 + (g + 1) * (2 * g + p) + c;   // partial slot

  int nt  = 2 * qt + 2;
  int kt0 = c * 8;
  int kt1 = min(nt, kt0 + 8);
  int qb0 = qt * 128;

  int tid = threadIdx.x;
  int lane = tid & 63, wv = tid >> 6;
  int l31 = lane & 31, h = lane >> 5, x = lane & 7;
  const short* Qp = Qb + (size_t)bh * SEQ * HD;
  const short* Kp = Kb + (size_t)bh * SEQ * HD;
  const short* Vp = VTb + (size_t)bh * HD * SEQ;

  int qs  = qb0 + wv * 32 + l31;
  int qlo = qb0 + wv * 32;
  int qhi = qlo + 31;

  short8 bq[4];
  #pragma unroll
  for (int dc = 0; dc < 4; ++dc)
    bq[dc] = ld8(Qp + qs * HD + dc * 16 + h * 8);

  int lr = lane >> 3;
  int cgc = (lane & 7) ^ lr;
  const short* kgl = Kp + (size_t)(kt0 * 64 + wv * 16 + lr) * HD + cgc * 8;
  const short* vgl = Vp + (size_t)(wv * 16 + lr) * SEQ + kt0 * 64 + cgc * 8;
  int wofs = wv * 2048;   // bytes within a buffer

  int rbase[4];
  #pragma unroll
  for (int kc = 0; kc < 4; ++kc)
    rbase[kc] = (l31 << 7) | ((((kc << 1) | h) ^ x) << 4);

  glds16(kgl,            (short*)(lds + wofs));
  glds16(kgl + 8 * HD,   (short*)(lds + wofs + 1024));
  glds16(vgl,            (short*)(lds + 16384 + wofs));
  glds16(vgl + 8 * SEQ,  (short*)(lds + 16384 + wofs + 1024));
  __syncthreads();

  floatx16 o0 = {}, o1 = {};
  float m_run = -1e30f, l_run = 0.f;

  for (int kt = kt0; kt < kt1; ++kt) {
    int cur = (kt - kt0) & 1;
    int curK = cur * 8192, curV = 16384 + cur * 8192;
    int kb = kt * 64;

    if (kt + 1 < kt1) {
      kgl += 64 * HD; vgl += 64;
      int nK = (cur ^ 1) * 8192, nV = 16384 + (cur ^ 1) * 8192;
      glds16(kgl,           (short*)(lds + nK + wofs));
      glds16(kgl + 8 * HD,  (short*)(lds + nK + wofs + 1024));
      glds16(vgl,           (short*)(lds + nV + wofs));
      glds16(vgl + 8 * SEQ, (short*)(lds + nV + wofs + 1024));
    }

    if (kb <= qhi) {
      floatx16 s0 = {}, s1 = {};
      #pragma unroll
      for (int kc = 0; kc < 4; ++kc) {
        short8 ka0 = *reinterpret_cast<const short8*>(lds + curK + rbase[kc]);
        short8 ka1 = *reinterpret_cast<const short8*>(lds + curK + 4096 + rbase[kc]);
        s0 = mfma32(ka0, bq[kc], s0);
        s1 = mfma32(ka1, bq[kc], s1);
      }
      if (kb + 63 > qlo) {
        #pragma unroll
        for (int r = 0; r < 16; ++r) {
          int kvr = kb + (r & 3) + 8 * (r >> 2) + 4 * h;
          s0[r] = (kvr > qs) ? -1e30f : s0[r];
          s1[r] = (kvr + 32 > qs) ? -1e30f : s1[r];
        }
      }
      float mloc = m_run;
      #pragma unroll
      for (int r = 0; r < 16; ++r) { mloc = fmaxf(mloc, s0[r]); mloc = fmaxf(mloc, s1[r]); }
      mloc = fmaxf(mloc, __shfl_xor(mloc, 32));
      float m_new = mloc;
      float alpha = __builtin_amdgcn_exp2f(m_run - m_new);
      float sloc = 0.f;
      #pragma unroll
      for (int r = 0; r < 16; ++r) {
        s0[r] = __builtin_amdgcn_exp2f(s0[r] - m_new); sloc += s0[r];
        s1[r] = __builtin_amdgcn_exp2f(s1[r] - m_new); sloc += s1[r];
      }
      sloc += __shfl_xor(sloc, 32);
      l_run = l_run * alpha + sloc;
      m_run = m_new;
      o0 *= alpha; o1 *= alpha;
      short8 pb[4];
      #pragma unroll
      for (int kvc = 0; kvc < 4; ++kvc) {
        int base = (kvc & 1) * 8;
        const floatx16& P = (kvc < 2) ? s0 : s1;
        unsigned e0 = pk2(P[base + 0], P[base + 1]);
        unsigned e1 = pk2(P[base + 2], P[base + 3]);
        unsigned f0 = pk2(P[base + 4], P[base + 5]);
        unsigned f1 = pk2(P[base + 6], P[base + 7]);
        unsigned k_0 = h ? f0 : e0, k_1 = h ? f1 : e1;
        unsigned s_0 = h ? e0 : f0, s_1 = h ? e1 : f1;
        unsigned r_0 = __shfl_xor((int)s_0, 32);
        unsigned r_1 = __shfl_xor((int)s_1, 32);
        union { unsigned u[4]; short8 v; } pbu;
        pbu.u[0] = h ? r_0 : k_0;
        pbu.u[1] = h ? r_1 : k_1;
        pbu.u[2] = h ? k_0 : r_0;
        pbu.u[3] = h ? k_1 : r_1;
        pb[kvc] = pbu.v;
      }
      #pragma unroll
      for (int kvc = 0; kvc < 4; ++kvc) {
        short8 va0 = *reinterpret_cast<const short8*>(lds + curV + rbase[kvc]);
        short8 va1 = *reinterpret_cast<const short8*>(lds + curV + 4096 + rbase[kvc]);
        o0 = mfma32(va0, pb[kvc], o0);
        o1 = mfma32(va1, pb[kvc], o1);
      }
    }
    __syncthreads();
  }

  int qloc = wv * 32 + l31;
  size_t pobase = (size_t)idx * 8192 + qloc * 64;
  #pragma unroll
  for (int dt = 0; dt < 2; ++dt) {
    #pragma unroll
    for (int cc = 0; cc < 4; ++cc) {
      int d = dt * 32 + 8 * cc + 4 * h;
      short4v w;
      #pragma unroll
      for (int r = 0; r < 4; ++r)
        w[r] = f2bf(dt ? o1[4 * cc + r] : o0[4 * cc + r]);
      *reinterpret_cast<short4v*>(PO + pobase + d) = w;
    }
  }
  if (h == 0) {
    PM[idx * 128 + qloc] = m_run;
    PL[idx * 128 + qloc] = l_run;
  }
}

// ---------------- GEMM2 with fused chunk-merge A-staging ----------------
// 64x128 tile. A = merged attention output, built on the fly from PO/PM/PL:
// prologue computes normalized weights w_c/sum(l_c w_c) per (head,row) into LDS;
// staging fma-merges nc bf16 partial chunks in fp32, packs, ds_write_b128 into
// the XOR-swizzled slot (slot = cc^((row>>1)&3)) the frag reads expect.
__global__ __launch_bounds__(256) void gemm_out_fused(const short* __restrict__ PO,
                                                      const float* __restrict__ PM,
                                                      const float* __restrict__ PL,
                                                      const short* __restrict__ WT,
                                                      const float* __restrict__ bias,
                                                      float* __restrict__ out) {
  __shared__ short As[64 * 32];
  __shared__ short Bs[128 * 32];
  __shared__ float Wts[12][64][4];   // [head][row][chunk] merged weight (w_c/wsum)
  int m0 = blockIdx.x * 64, n0 = blockIdx.y * 128;
  int b  = m0 >> 11;
  int s0 = m0 & 2047;
  int qt = s0 >> 7;
  int g = qt >> 2, p = qt & 3;
  int nc = g + 1;                       // 1..4, block-uniform
  int off = (g + 1) * (2 * g + p);
  int tid = threadIdx.x;

  // prologue: merge weights for all (head,row)
  for (int pp = tid; pp < 768; pp += 256) {
    int row = pp & 63, hh = pp >> 6;
    int qloc = (s0 + row) & 127;
    int ib = (b * NH + hh) * 40 + off;
    float m[4], l[4], M = -1e30f;
    for (int c = 0; c < nc; ++c) {
      m[c] = PM[(ib + c) * 128 + qloc];
      l[c] = PL[(ib + c) * 128 + qloc];
      M = fmaxf(M, m[c]);
    }
    float wsum = 0.f, w[4];
    for (int c = 0; c < nc; ++c) { w[c] = __builtin_amdgcn_exp2f(m[c] - M); wsum += l[c] * w[c]; }
    float inv = 1.f / wsum;
    for (int c = 0; c < nc; ++c) Wts[hh][row][c] = w[c] * inv;
  }

  int lane = tid & 63, wv = tid >> 6;
  int wm = (wv >> 1) << 5;   // 0 / 32
  int wn = (wv & 1) << 6;    // 0 / 64
  int quad = lane >> 4, l16 = lane & 15;

  // A staging: lane -> row (wv*16 + lane>>2), 16B chunk cc = lane&3
  int lr = lane >> 2, cc = lane & 3;
  int row_in_blk = wv * 16 + lr;
  int qloc_a = (s0 + row_in_blk) & 127;
  short* awr = As + row_in_blk * 32 + ((cc ^ ((lr >> 1) & 3)) << 3);
  size_t pbase = (size_t)(b * NH * 40 + off) * 8192 + qloc_a * 64 + cc * 8;

  // B staging (DMA, as before)
  int srow = lane >> 2;
  int schunk = (lane & 3) ^ ((lane >> 3) & 3);
  const short* bg0 = WT + (size_t)(n0 + wv * 32 + srow) * HIDDEN + schunk * 8;
  const short* bg1 = bg0 + 16 * HIDDEN;
  short* lB0 = Bs + wv * 1024;

  int sw = ((l16 >> 1) & 3);
  int aoff = (wm + l16) * 32 + ((quad ^ sw) << 3);
  int boff = (wn + l16) * 32 + ((quad ^ sw) << 3);

  floatx4 acc[2][4] = {};
  for (int kk = 0; kk < HIDDEN; kk += 32) {
    __syncthreads();   // covers prologue Wts writes on first iter
    glds16(bg0, lB0);
    glds16(bg1, lB0 + 512);
    bg0 += 32; bg1 += 32;
    {
      int hh = kk >> 6, dh0 = kk & 63;   // dh0 in {0,32}
      const short* pp0 = PO + (size_t)hh * 40 * 8192 + pbase + dh0;
      const float* wr = Wts[hh][row_in_blk];
      float a[8] = {};
      for (int c = 0; c < nc; ++c) {
        short8 v = ld8(pp0 + c * 8192);
        float wc = wr[c];
        #pragma unroll
        for (int e = 0; e < 8; ++e) a[e] += wc * bf2f(v[e]);
      }
      short8 av;
      #pragma unroll
      for (int e = 0; e < 8; ++e) av[e] = f2bf(a[e]);
      *reinterpret_cast<short8*>(awr) = av;
    }
    __syncthreads();
    short8 af[2], bfr[4];
    #pragma unroll
    for (int i = 0; i < 2; ++i)
      af[i] = *reinterpret_cast<const short8*>(&As[aoff + i * 512]);
    #pragma unroll
    for (int j = 0; j < 4; ++j)
      bfr[j] = *reinterpret_cast<const short8*>(&Bs[boff + j * 512]);
    #pragma unroll
    for (int i = 0; i < 2; ++i)
      #pragma unroll
      for (int j = 0; j < 4; ++j)
        acc[i][j] = mfma_bf16(af[i], bfr[j], acc[i][j]);
  }
  #pragma unroll
  for (int j = 0; j < 4; ++j) {
    int col = n0 + wn + j * 16 + l16;
    float bs = bias[col];
    #pragma unroll
    for (int i = 0; i < 2; ++i) {
      #pragma unroll
      for (int r = 0; r < 4; ++r) {
        int row = m0 + wm + i * 16 + quad * 4 + r;
        out[(size_t)row * HIDDEN + col] = acc[i][j][r] + bs;
      }
    }
  }
}

extern "C" void kernel_launch(void* const* d_in, const int* in_sizes, int n_in,
                              void* d_out, int out_size, void* d_ws, size_t ws_size,
                              hipStream_t stream) {
  const float* x    = (const float*)d_in[0];
  const float* Wqkv = (const float*)d_in[1];
  const float* bqkv = (const float*)d_in[2];
  const float* Wout = (const float*)d_in[3];
  const float* bout = (const float*)d_in[4];
  float* out = (float*)d_out;

  short* WqkvT = (short*)d_ws;                     // [2304][768]
  short* WoutT = WqkvT + (size_t)NQKV * HIDDEN;    // [768][768]
  short* Qb    = WoutT + (size_t)HIDDEN * HIDDEN;  // [24][2048][64] (log2-domain scale)
  short* Kb    = Qb + (size_t)BHN * SEQ * HD;
  short* VTb   = Kb + (size_t)BHN * SEQ * HD;      // [24][64][2048]
  short* AO    = VTb + (size_t)BHN * SEQ * HD;     // (unused now; layout kept)
  short* Xb    = AO + (size_t)MTOT * HIDDEN;       // [4096][768] (dead after gemm_qkv)
  short* PO    = Xb;                               // aliases Xb: 960*8192 bf16 partials
  float* PM    = (float*)(PO + (size_t)960 * 8192);
  float* PL    = PM + 960 * 128;

  prep<<<dim3(2112), 256, 0, stream>>>(x, Wqkv, Wout, Xb, WqkvT, WoutT);
  gemm_qkv<<<dim3(MTOT / 128, NQKV / 128), 256, 0, stream>>>(Xb, WqkvT, bqkv, Qb, Kb, VTb);
  attn_partial<<<dim3(960), 256, 0, stream>>>(Qb, Kb, VTb, PO, PM, PL);
  gemm_out_fused<<<dim3(MTOT / 64, HIDDEN / 128), 256, 0, stream>>>(PO, PM, PL, WoutT, bout, out);
}

// Round 11
// 156.617 us; speedup vs baseline: 1.0986x; 1.0986x over previous
//
#include <hip/hip_runtime.h>

typedef __attribute__((ext_vector_type(8))) short short8;
typedef __attribute__((ext_vector_type(4))) short short4v;
typedef __attribute__((ext_vector_type(4))) float floatx4;
typedef __attribute__((ext_vector_type(16))) float floatx16;

#define HIDDEN 768
#define NH 12
#define HD 64
#define SEQ 2048
#define BATCH 2
#define BHN (BATCH*NH)      // 24
#define MTOT (BATCH*SEQ)    // 4096
#define NQKV (3*HIDDEN)     // 2304
#define QSCALE 0.1803368801111204f   // 0.125 * log2(e): scores in log2 domain

__device__ __forceinline__ short f2bf(float f) {
  union { float f; unsigned u; } v; v.f = f;
  unsigned r = v.u + 0x7FFFu + ((v.u >> 16) & 1u);   // RNE
  return (short)(r >> 16);
}
__device__ __forceinline__ unsigned bfrne(float f) {
  unsigned u = __float_as_uint(f);
  return u + 0x7FFFu + ((u >> 16) & 1u);
}
__device__ __forceinline__ unsigned pk2(float a, float b) {
  return __builtin_amdgcn_perm(bfrne(b), bfrne(a), 0x07060302u);
}
__device__ __forceinline__ float bf2f(short s) {
  return __uint_as_float(((unsigned)(unsigned short)s) << 16);
}
__device__ __forceinline__ floatx4 mfma_bf16(short8 a, short8 b, floatx4 c) {
  return __builtin_amdgcn_mfma_f32_16x16x32_bf16(a, b, c, 0, 0, 0);
}
__device__ __forceinline__ floatx16 mfma32(short8 a, short8 b, floatx16 c) {
  return __builtin_amdgcn_mfma_f32_32x32x16_bf16(a, b, c, 0, 0, 0);
}
__device__ __forceinline__ short8 ld8(const short* p) {
  return *reinterpret_cast<const short8*>(p);
}
// async global->LDS DMA, 16B per lane. LDS dst = wave-uniform base + lane*16.
__device__ __forceinline__ void glds16(const short* g, short* l) {
  __builtin_amdgcn_global_load_lds(
      (const __attribute__((address_space(1))) void*)g,
      (__attribute__((address_space(3))) void*)l, 16, 0, 0);
}

// ---------------- fused prep: X cvt + both weight transposes, one launch ----------------
__global__ __launch_bounds__(256) void prep(const float* __restrict__ X,
                                            const float* __restrict__ Wqkv,
                                            const float* __restrict__ Wout,
                                            short* __restrict__ Xb,
                                            short* __restrict__ WqkvT,
                                            short* __restrict__ WoutT) {
  __shared__ short t[64][72];
  int bx = blockIdx.x;
  if (bx < 1536) {
    int i = (bx * 256 + threadIdx.x) * 8;
    const float4* s = reinterpret_cast<const float4*>(X + i);
    float4 v0 = s[0], v1 = s[1];
    short8 o;
    o[0] = f2bf(v0.x); o[1] = f2bf(v0.y); o[2] = f2bf(v0.z); o[3] = f2bf(v0.w);
    o[4] = f2bf(v1.x); o[5] = f2bf(v1.y); o[6] = f2bf(v1.z); o[7] = f2bf(v1.w);
    *reinterpret_cast<short8*>(Xb + i) = o;
    return;
  }
  int tt = bx - 1536;            // 0..575
  int bxx = tt % 48, by = tt / 48;
  const float* W; short* WT; int N; int nb;
  if (bxx < 36) { W = Wqkv; WT = WqkvT; N = NQKV;   nb = bxx * 64; }
  else          { W = Wout; WT = WoutT; N = HIDDEN; nb = (bxx - 36) * 64; }
  int kb = by * 64;
  int tid = threadIdx.x;
  {
    int k  = tid >> 2;
    int n0 = (tid & 3) << 4;
    const float4* src = reinterpret_cast<const float4*>(W + (size_t)(kb + k) * N + nb + n0);
    #pragma unroll
    for (int c = 0; c < 4; ++c) {
      float4 v = src[c];
      t[n0 + c*4 + 0][k] = f2bf(v.x);
      t[n0 + c*4 + 1][k] = f2bf(v.y);
      t[n0 + c*4 + 2][k] = f2bf(v.z);
      t[n0 + c*4 + 3][k] = f2bf(v.w);
    }
  }
  __syncthreads();
  {
    int n  = tid >> 2;
    int k0 = (tid & 3) << 4;
    const short8* row = reinterpret_cast<const short8*>(&t[n][k0]);
    short8* dst = reinterpret_cast<short8*>(WT + (size_t)(nb + n) * HIDDEN + kb + k0);
    dst[0] = row[0];
    dst[1] = row[1];
  }
}

// ---------------- GEMM1: 128x128 tile, BK=32, glds16 staging (R8 known-good) ----------------
__global__ __launch_bounds__(256) void gemm_qkv(const short* __restrict__ Xb,
                                                const short* __restrict__ WT,
                                                const float* __restrict__ bias,
                                                short* __restrict__ Qb,
                                                short* __restrict__ Kb,
                                                short* __restrict__ VTb) {
  __shared__ short As[128 * 32];
  __shared__ short Bs[128 * 32];
  int m0 = blockIdx.x * 128, n0 = blockIdx.y * 128;
  int tid = threadIdx.x;
  int lane = tid & 63, wv = tid >> 6;
  int wm = (wv >> 1) << 6, wn = (wv & 1) << 6;
  int quad = lane >> 4, l16 = lane & 15;

  int srow = lane >> 2;
  int schunk = (lane & 3) ^ ((lane >> 3) & 3);
  const short* ag0 = Xb + (size_t)(m0 + wv * 32 + srow) * HIDDEN + schunk * 8;
  const short* ag1 = ag0 + 16 * HIDDEN;
  const short* bg0 = WT + (size_t)(n0 + wv * 32 + srow) * HIDDEN + schunk * 8;
  const short* bg1 = bg0 + 16 * HIDDEN;
  short* lA0 = As + wv * 1024;
  short* lB0 = Bs + wv * 1024;

  int sw = ((l16 >> 1) & 3);
  int aoff = (wm + l16) * 32 + ((quad ^ sw) << 3);
  int boff = (wn + l16) * 32 + ((quad ^ sw) << 3);

  floatx4 acc[4][4] = {};
  for (int kk = 0; kk < HIDDEN; kk += 32) {
    __syncthreads();
    glds16(ag0, lA0);
    glds16(ag1, lA0 + 512);
    glds16(bg0, lB0);
    glds16(bg1, lB0 + 512);
    ag0 += 32; ag1 += 32; bg0 += 32; bg1 += 32;
    __syncthreads();
    short8 af[4], bfr[4];
    #pragma unroll
    for (int i = 0; i < 4; ++i)
      af[i] = *reinterpret_cast<const short8*>(&As[aoff + i * 512]);
    #pragma unroll
    for (int j = 0; j < 4; ++j)
      bfr[j] = *reinterpret_cast<const short8*>(&Bs[boff + j * 512]);
    #pragma unroll
    for (int i = 0; i < 4; ++i)
      #pragma unroll
      for (int j = 0; j < 4; ++j)
        acc[i][j] = mfma_bf16(af[i], bfr[j], acc[i][j]);
  }
  int colbase = n0 + wn;
  int part = colbase / HIDDEN;
  #pragma unroll
  for (int j = 0; j < 4; ++j) {
    int col = colbase + j * 16 + l16;
    float bs = bias[col];
    int rem = col - part * HIDDEN;
    int h = rem >> 6, d = rem & 63;
    #pragma unroll
    for (int i = 0; i < 4; ++i) {
      #pragma unroll
      for (int r = 0; r < 4; ++r) {
        int row = m0 + wm + i * 16 + quad * 4 + r;
        float v = acc[i][j][r] + bs;
        int bb = row >> 11, s = row & 2047;
        int bh = bb * NH + h;
        if (part == 0) {
          Qb[((size_t)bh * SEQ + s) * HD + d] = f2bf(v * QSCALE);
        } else if (part == 1) {
          Kb[((size_t)bh * SEQ + s) * HD + d] = f2bf(v);
        } else {
          VTb[((size_t)bh * HD + d) * SEQ + s] = f2bf(v);
        }
      }
    }
  }
}

// ---------------- flash attention partials: uniform 512-kv chunks ----------------
// K/V^T staged via global_load_lds, XOR swizzle on the global address side.
// qt<4 (single chunk): result is final -> normalize and write AO directly.
__global__ __launch_bounds__(256, 4) void attn_partial(const short* __restrict__ Qb,
                                                       const short* __restrict__ Kb,
                                                       const short* __restrict__ VTb,
                                                       short* __restrict__ PO,
                                                       float* __restrict__ PM,
                                                       float* __restrict__ PL,
                                                       short* __restrict__ AO) {
  __shared__ __align__(16) char lds[32768];   // K: buf*8192 ; V: 16384 + buf*8192
  int blk = blockIdx.x;
  int cls = blk & 7;
  int j   = blk >> 3;            // 0..119
  int headsel = j / 40;
  int bh  = cls + 8 * headsel;
  int cidx = 39 - (j - headsel * 40);   // heavy first
  int qt, c;
  if (cidx < 4)       { qt = cidx;                  c = 0; }
  else if (cidx < 12) { qt = 4 + ((cidx - 4) >> 1); c = (cidx - 4) & 1; }
  else if (cidx < 24) { int t = cidx - 12; int q3 = t / 3; qt = 8 + q3; c = t - 3 * q3; }
  else                { int t = cidx - 24; qt = 12 + (t >> 2); c = t & 3; }
  int g = qt >> 2, p = qt & 3;
  int idx = bh * 40 + (g + 1) * (2 * g + p) + c;   // partial slot

  int nt  = 2 * qt + 2;
  int kt0 = c * 8;
  int kt1 = min(nt, kt0 + 8);
  int qb0 = qt * 128;

  int tid = threadIdx.x;
  int lane = tid & 63, wv = tid >> 6;
  int l31 = lane & 31, h = lane >> 5, x = lane & 7;
  const short* Qp = Qb + (size_t)bh * SEQ * HD;
  const short* Kp = Kb + (size_t)bh * SEQ * HD;
  const short* Vp = VTb + (size_t)bh * HD * SEQ;

  int qs  = qb0 + wv * 32 + l31;
  int qlo = qb0 + wv * 32;
  int qhi = qlo + 31;

  short8 bq[4];
  #pragma unroll
  for (int dc = 0; dc < 4; ++dc)
    bq[dc] = ld8(Qp + qs * HD + dc * 16 + h * 8);

  int lr = lane >> 3;
  int cgc = (lane & 7) ^ lr;
  const short* kgl = Kp + (size_t)(kt0 * 64 + wv * 16 + lr) * HD + cgc * 8;
  const short* vgl = Vp + (size_t)(wv * 16 + lr) * SEQ + kt0 * 64 + cgc * 8;
  int wofs = wv * 2048;   // bytes within a buffer

  int rbase[4];
  #pragma unroll
  for (int kc = 0; kc < 4; ++kc)
    rbase[kc] = (l31 << 7) | ((((kc << 1) | h) ^ x) << 4);

  glds16(kgl,            (short*)(lds + wofs));
  glds16(kgl + 8 * HD,   (short*)(lds + wofs + 1024));
  glds16(vgl,            (short*)(lds + 16384 + wofs));
  glds16(vgl + 8 * SEQ,  (short*)(lds + 16384 + wofs + 1024));
  __syncthreads();

  floatx16 o0 = {}, o1 = {};
  float m_run = -1e30f, l_run = 0.f;

  for (int kt = kt0; kt < kt1; ++kt) {
    int cur = (kt - kt0) & 1;
    int curK = cur * 8192, curV = 16384 + cur * 8192;
    int kb = kt * 64;

    if (kt + 1 < kt1) {
      kgl += 64 * HD; vgl += 64;
      int nK = (cur ^ 1) * 8192, nV = 16384 + (cur ^ 1) * 8192;
      glds16(kgl,           (short*)(lds + nK + wofs));
      glds16(kgl + 8 * HD,  (short*)(lds + nK + wofs + 1024));
      glds16(vgl,           (short*)(lds + nV + wofs));
      glds16(vgl + 8 * SEQ, (short*)(lds + nV + wofs + 1024));
    }

    if (kb <= qhi) {
      floatx16 s0 = {}, s1 = {};
      #pragma unroll
      for (int kc = 0; kc < 4; ++kc) {
        short8 ka0 = *reinterpret_cast<const short8*>(lds + curK + rbase[kc]);
        short8 ka1 = *reinterpret_cast<const short8*>(lds + curK + 4096 + rbase[kc]);
        s0 = mfma32(ka0, bq[kc], s0);
        s1 = mfma32(ka1, bq[kc], s1);
      }
      if (kb + 63 > qlo) {
        #pragma unroll
        for (int r = 0; r < 16; ++r) {
          int kvr = kb + (r & 3) + 8 * (r >> 2) + 4 * h;
          s0[r] = (kvr > qs) ? -1e30f : s0[r];
          s1[r] = (kvr + 32 > qs) ? -1e30f : s1[r];
        }
      }
      float mloc = m_run;
      #pragma unroll
      for (int r = 0; r < 16; ++r) { mloc = fmaxf(mloc, s0[r]); mloc = fmaxf(mloc, s1[r]); }
      mloc = fmaxf(mloc, __shfl_xor(mloc, 32));
      float m_new = mloc;
      float alpha = __builtin_amdgcn_exp2f(m_run - m_new);
      float sloc = 0.f;
      #pragma unroll
      for (int r = 0; r < 16; ++r) {
        s0[r] = __builtin_amdgcn_exp2f(s0[r] - m_new); sloc += s0[r];
        s1[r] = __builtin_amdgcn_exp2f(s1[r] - m_new); sloc += s1[r];
      }
      sloc += __shfl_xor(sloc, 32);
      l_run = l_run * alpha + sloc;
      m_run = m_new;
      o0 *= alpha; o1 *= alpha;
      short8 pb[4];
      #pragma unroll
      for (int kvc = 0; kvc < 4; ++kvc) {
        int base = (kvc & 1) * 8;
        const floatx16& P = (kvc < 2) ? s0 : s1;
        unsigned e0 = pk2(P[base + 0], P[base + 1]);
        unsigned e1 = pk2(P[base + 2], P[base + 3]);
        unsigned f0 = pk2(P[base + 4], P[base + 5]);
        unsigned f1 = pk2(P[base + 6], P[base + 7]);
        unsigned k_0 = h ? f0 : e0, k_1 = h ? f1 : e1;
        unsigned s_0 = h ? e0 : f0, s_1 = h ? e1 : f1;
        unsigned r_0 = __shfl_xor((int)s_0, 32);
        unsigned r_1 = __shfl_xor((int)s_1, 32);
        union { unsigned u[4]; short8 v; } pbu;
        pbu.u[0] = h ? r_0 : k_0;
        pbu.u[1] = h ? r_1 : k_1;
        pbu.u[2] = h ? k_0 : r_0;
        pbu.u[3] = h ? k_1 : r_1;
        pb[kvc] = pbu.v;
      }
      #pragma unroll
      for (int kvc = 0; kvc < 4; ++kvc) {
        short8 va0 = *reinterpret_cast<const short8*>(lds + curV + rbase[kvc]);
        short8 va1 = *reinterpret_cast<const short8*>(lds + curV + 4096 + rbase[kvc]);
        o0 = mfma32(va0, pb[kvc], o0);
        o1 = mfma32(va1, pb[kvc], o1);
      }
    }
    __syncthreads();
  }

  int qloc = wv * 32 + l31;
  if (qt < 4) {
    // single-chunk tile: this partial IS the final output -> normalize, write AO
    float inv = 1.f / l_run;
    int b2 = bh / NH, hh2 = bh % NH;
    size_t obase = ((size_t)(b2 * SEQ + qb0 + qloc)) * HIDDEN + hh2 * HD;
    #pragma unroll
    for (int dt = 0; dt < 2; ++dt) {
      #pragma unroll
      for (int cc = 0; cc < 4; ++cc) {
        int d = dt * 32 + 8 * cc + 4 * h;
        short4v w;
        #pragma unroll
        for (int r = 0; r < 4; ++r)
          w[r] = f2bf((dt ? o1[4 * cc + r] : o0[4 * cc + r]) * inv);
        *reinterpret_cast<short4v*>(AO + obase + d) = w;
      }
    }
  } else {
    size_t pobase = (size_t)idx * 8192 + qloc * 64;
    #pragma unroll
    for (int dt = 0; dt < 2; ++dt) {
      #pragma unroll
      for (int cc = 0; cc < 4; ++cc) {
        int d = dt * 32 + 8 * cc + 4 * h;
        short4v w;
        #pragma unroll
        for (int r = 0; r < 4; ++r)
          w[r] = f2bf(dt ? o1[4 * cc + r] : o0[4 * cc + r]);
        *reinterpret_cast<short4v*>(PO + pobase + d) = w;
      }
    }
    if (h == 0) {
      PM[idx * 128 + qloc] = m_run;
      PL[idx * 128 + qloc] = l_run;
    }
  }
}

// ---------------- merge partial chunks -> AO (qt >= 4 only) ----------------
__global__ __launch_bounds__(256) void attn_merge(const short* __restrict__ PO,
                                                  const float* __restrict__ PM,
                                                  const float* __restrict__ PL,
                                                  short* __restrict__ AO) {
  int blk = blockIdx.x;
  int bh = blk / 12, qt = 4 + blk % 12;
  int g = qt >> 2, p = qt & 3;
  int base = bh * 40 + (g + 1) * (2 * g + p);
  int nc = g + 1;
  int tid = threadIdx.x;
  int q = tid >> 1, dh = (tid & 1) << 5;
  float mv[4];
  float M = -1e30f;
  for (int c = 0; c < nc; ++c) {
    mv[c] = PM[(base + c) * 128 + q];
    M = fmaxf(M, mv[c]);
  }
  float wsum = 0.f;
  float acc[32] = {};
  for (int c = 0; c < nc; ++c) {
    float w = __builtin_amdgcn_exp2f(mv[c] - M);
    wsum += PL[(base + c) * 128 + q] * w;
    const short8* po = reinterpret_cast<const short8*>(PO + (size_t)(base + c) * 8192 + q * 64 + dh);
    #pragma unroll
    for (int k = 0; k < 4; ++k) {
      short8 v = po[k];
      #pragma unroll
      for (int e = 0; e < 8; ++e)
        acc[k * 8 + e] += w * bf2f(v[e]);
    }
  }
  float inv = 1.f / wsum;
  int b = bh / NH, hh = bh % NH;
  int s = qt * 128 + q;
  short* dst = AO + ((size_t)(b * SEQ + s)) * HIDDEN + hh * HD + dh;
  #pragma unroll
  for (int k = 0; k < 4; ++k) {
    short8 w8;
    #pragma unroll
    for (int e = 0; e < 8; ++e)
      w8[e] = f2bf(acc[k * 8 + e] * inv);
    *reinterpret_cast<short8*>(dst + k * 8) = w8;
  }
}

// ---------------- GEMM2: 64x128 tile, BK=32 (R8 known-good) ----------------
__global__ __launch_bounds__(256) void gemm_out(const short* __restrict__ AO,
                                                const short* __restrict__ WT,
                                                const float* __restrict__ bias,
                                                float* __restrict__ out) {
  __shared__ short As[64 * 32];
  __shared__ short Bs[128 * 32];
  int m0 = blockIdx.x * 64, n0 = blockIdx.y * 128;
  int tid = threadIdx.x;
  int lane = tid & 63, wv = tid >> 6;
  int wm = (wv >> 1) << 5;   // 0 / 32
  int wn = (wv & 1) << 6;    // 0 / 64
  int quad = lane >> 4, l16 = lane & 15;

  int srow = lane >> 2;
  int schunk = (lane & 3) ^ ((lane >> 3) & 3);
  const short* ag  = AO + (size_t)(m0 + wv * 16 + srow) * HIDDEN + schunk * 8;
  const short* bg0 = WT + (size_t)(n0 + wv * 32 + srow) * HIDDEN + schunk * 8;
  const short* bg1 = bg0 + 16 * HIDDEN;
  short* lA  = As + wv * 512;    // 16 rows
  short* lB0 = Bs + wv * 1024;   // 32 rows

  int sw = ((l16 >> 1) & 3);
  int aoff = (wm + l16) * 32 + ((quad ^ sw) << 3);
  int boff = (wn + l16) * 32 + ((quad ^ sw) << 3);

  floatx4 acc[2][4] = {};
  for (int kk = 0; kk < HIDDEN; kk += 32) {
    __syncthreads();
    glds16(ag, lA);
    glds16(bg0, lB0);
    glds16(bg1, lB0 + 512);
    ag += 32; bg0 += 32; bg1 += 32;
    __syncthreads();
    short8 af[2], bfr[4];
    #pragma unroll
    for (int i = 0; i < 2; ++i)
      af[i] = *reinterpret_cast<const short8*>(&As[aoff + i * 512]);
    #pragma unroll
    for (int j = 0; j < 4; ++j)
      bfr[j] = *reinterpret_cast<const short8*>(&Bs[boff + j * 512]);
    #pragma unroll
    for (int i = 0; i < 2; ++i)
      #pragma unroll
      for (int j = 0; j < 4; ++j)
        acc[i][j] = mfma_bf16(af[i], bfr[j], acc[i][j]);
  }
  #pragma unroll
  for (int j = 0; j < 4; ++j) {
    int col = n0 + wn + j * 16 + l16;
    float bs = bias[col];
    #pragma unroll
    for (int i = 0; i < 2; ++i) {
      #pragma unroll
      for (int r = 0; r < 4; ++r) {
        int row = m0 + wm + i * 16 + quad * 4 + r;
        out[(size_t)row * HIDDEN + col] = acc[i][j][r] + bs;
      }
    }
  }
}

extern "C" void kernel_launch(void* const* d_in, const int* in_sizes, int n_in,
                              void* d_out, int out_size, void* d_ws, size_t ws_size,
                              hipStream_t stream) {
  const float* x    = (const float*)d_in[0];
  const float* Wqkv = (const float*)d_in[1];
  const float* bqkv = (const float*)d_in[2];
  const float* Wout = (const float*)d_in[3];
  const float* bout = (const float*)d_in[4];
  float* out = (float*)d_out;

  short* WqkvT = (short*)d_ws;                     // [2304][768]
  short* WoutT = WqkvT + (size_t)NQKV * HIDDEN;    // [768][768]
  short* Qb    = WoutT + (size_t)HIDDEN * HIDDEN;  // [24][2048][64] (log2-domain scale)
  short* Kb    = Qb + (size_t)BHN * SEQ * HD;
  short* VTb   = Kb + (size_t)BHN * SEQ * HD;      // [24][64][2048]
  short* AO    = VTb + (size_t)BHN * SEQ * HD;     // [4096][768]
  short* Xb    = AO + (size_t)MTOT * HIDDEN;       // [4096][768] (dead after gemm_qkv)
  short* PO    = Xb;                               // aliases Xb: 960*8192 bf16 partials
  float* PM    = (float*)(PO + (size_t)960 * 8192);
  float* PL    = PM + 960 * 128;

  prep<<<dim3(2112), 256, 0, stream>>>(x, Wqkv, Wout, Xb, WqkvT, WoutT);
  gemm_qkv<<<dim3(MTOT / 128, NQKV / 128), 256, 0, stream>>>(Xb, WqkvT, bqkv, Qb, Kb, VTb);
  attn_partial<<<dim3(960), 256, 0, stream>>>(Qb, Kb, VTb, PO, PM, PL, AO);
  attn_merge<<<dim3(BHN * 12), 256, 0, stream>>>(PO, PM, PL, AO);
  gemm_out<<<dim3(MTOT / 64, HIDDEN / 128), 256, 0, stream>>>(AO, WoutT, bout, out);
}